// Round 4
// baseline (733.426 us; speedup 1.0000x reference)
//
#include <hip/hip_runtime.h>
#include <hip/hip_bf16.h>

typedef __bf16 bf16x8 __attribute__((ext_vector_type(8)));
typedef __bf16 bf16x4 __attribute__((ext_vector_type(4)));
typedef float  f32x4  __attribute__((ext_vector_type(4)));

#define T_TOK    8192
#define D_DIM    1024
#define H_DIM    2048
#define E_NUM    8
#define MAX_ROWS 17408    // 136*128 (regions padded to 128 rows, as before)
#define MAX_MB256 72      // sum ceil(ceil(n_e/128)/2) <= (136+8)/2 = 72

// ---- workspace layout (bytes) ---- (unchanged from proven layout; +MBEND table)
#define OFF_MBTOT   512
#define OFF_MB2E    1024
#define OFF_MBROW0  2048
#define OFF_MBEND   3072
#define OFF_TOPKE   4096            // 16384 ints  -> ends 69632
#define OFF_TOPKS   69632           // 16384 float -> ends 135168
#define OFF_TOK     135168          // 17408 ints  -> ends 204800
#define OFF_ROWIDX  204800          // 16384 ints  -> ends 270336
#define OFF_XB      (1u<<20)                    // 8192*1024*2  = 16 MiB
#define OFF_W1T     (18u*1024*1024)             // 8*2048*1024*2 = 32 MiB -> ends 50 MiB
#define OFF_W2T     (50u*1024*1024)             // 8*1024*2048*2 = 32 MiB -> ends 82 MiB
#define OFF_HBUF    (82u*1024*1024)             // 17408*2048*2  = 68 MiB -> ends 150 MiB
#define OFF_YBUF    OFF_XB                      // overlay: xb+W1T dead after gemm1

__device__ __forceinline__ void gload_lds16(const void* g, void* l) {
    __builtin_amdgcn_global_load_lds(
        (const __attribute__((address_space(1))) void*)g,
        (__attribute__((address_space(3))) void*)l, 16, 0, 0);
}

// ---------------- fused router (+ fp32->bf16 convert of x), NO atomics ----------------
__global__ __launch_bounds__(256) void k_router_cvt(
    const float* __restrict__ x, const float* __restrict__ Wg,
    __bf16* __restrict__ xb, int* __restrict__ topk_e, float* __restrict__ topk_s)
{
    __shared__ float wgT[E_NUM][1032];   // padded stride
    const int tid = threadIdx.x;
#pragma unroll
    for (int i = 0; i < 32; ++i) {
        int f = tid + i * 256;           // coalesced read of Wg[1024][8]
        wgT[f & 7][f >> 3] = Wg[f];
    }
    __syncthreads();

    const int wave = tid >> 6, lane = tid & 63;
    const int t = blockIdx.x * 4 + wave;
    const float* xr = x + (size_t)t * D_DIM;
    __bf16* xbr = xb + (size_t)t * D_DIM;

    float acc[E_NUM];
#pragma unroll
    for (int e = 0; e < E_NUM; ++e) acc[e] = 0.f;

#pragma unroll
    for (int j = 0; j < 4; ++j) {
        const int d0 = lane * 4 + j * 256;
        float4 xv = *(const float4*)(xr + d0);
        bf16x4 o = { (__bf16)xv.x, (__bf16)xv.y, (__bf16)xv.z, (__bf16)xv.w };
        *(bf16x4*)(xbr + d0) = o;
#pragma unroll
        for (int e = 0; e < E_NUM; ++e) {
            float4 wv = *(const float4*)&wgT[e][d0];
            acc[e] += xv.x * wv.x + xv.y * wv.y + xv.z * wv.z + xv.w * wv.w;
        }
    }
#pragma unroll
    for (int off = 32; off >= 1; off >>= 1)
#pragma unroll
        for (int e = 0; e < E_NUM; ++e) acc[e] += __shfl_xor(acc[e], off, 64);

    if (lane == 0) {
        int e0 = 0; float v0 = acc[0];
#pragma unroll
        for (int e = 1; e < E_NUM; ++e) if (acc[e] > v0) { v0 = acc[e]; e0 = e; }
        int e1 = -1; float v1 = -1e30f;
#pragma unroll
        for (int e = 0; e < E_NUM; ++e) if (e != e0 && acc[e] > v1) { v1 = acc[e]; e1 = e; }
        float s0 = 1.f / (1.f + __expf(v1 - v0));  // renormalized top-2 softmax
        float s1 = 1.f - s0;
        topk_e[t*2+0] = e0; topk_e[t*2+1] = e1;
        topk_s[t*2+0] = s0; topk_s[t*2+1] = s1;
    }
}

// ---------------- single-block counting sort ----------------
#define SORT_T 256
__global__ __launch_bounds__(512) void k_sort(
    const int* __restrict__ topk_e,
    int* __restrict__ mbTot, int* __restrict__ mb2e, int* __restrict__ mbrow0,
    int* __restrict__ mbrowEnd, int* __restrict__ tok, int* __restrict__ rowidx)
{
    __shared__ int lcnt[E_NUM][SORT_T];
    __shared__ int base[E_NUM];
    __shared__ int etot[E_NUM];
    const int tid = threadIdx.x;

    if (tid < SORT_T) {
#pragma unroll
        for (int e = 0; e < E_NUM; ++e) lcnt[e][tid] = 0;
    }
    __syncthreads();

    if (tid < SORT_T) {
        const int4* p = (const int4*)(topk_e + tid * 64);
#pragma unroll
        for (int i = 0; i < 16; ++i) {
            int4 v = p[i];
            lcnt[v.x][tid]++; lcnt[v.y][tid]++; lcnt[v.z][tid]++; lcnt[v.w][tid]++;
        }
    }
    __syncthreads();

    {
        const int w = tid >> 6, l = tid & 63;
        int v0 = lcnt[w][l*4+0], v1 = lcnt[w][l*4+1], v2 = lcnt[w][l*4+2], v3 = lcnt[w][l*4+3];
        int s = v0 + v1 + v2 + v3;
        int inc = s;
#pragma unroll
        for (int off = 1; off < 64; off <<= 1) {
            int o = __shfl_up(inc, off, 64);
            if (l >= off) inc += o;
        }
        int exc = inc - s;
        lcnt[w][l*4+0] = exc;
        lcnt[w][l*4+1] = exc + v0;
        lcnt[w][l*4+2] = exc + v0 + v1;
        lcnt[w][l*4+3] = exc + v0 + v1 + v2;
        if (l == 63) etot[w] = inc;
    }
    __syncthreads();

    // serial (8 experts): 128-padded row regions, 256-row M-block tables
    if (tid == 0) {
        int row = 0, mb = 0;
        for (int e = 0; e < E_NUM; ++e) {
            base[e] = row;
            int nb128 = (etot[e] + 127) >> 7;
            int len   = nb128 << 7;
            int nb    = (nb128 + 1) >> 1;          // 256-row blocks
            for (int b = 0; b < nb; ++b) {
                mb2e[mb]   = e;
                mbrow0[mb] = row + b * 256;
                int re = row + len, be = row + b * 256 + 256;
                mbrowEnd[mb] = re < be ? re : be;
                ++mb;
            }
            row += len;
        }
        mbTot[0] = mb;
        mbTot[1] = row;   // rowTot (128-padded total)
    }
    __syncthreads();

    if (tid < SORT_T) {
#pragma unroll
        for (int e = 0; e < E_NUM; ++e) lcnt[e][tid] += base[e];
        const int4* p = (const int4*)(topk_e + tid * 64);
#pragma unroll
        for (int i = 0; i < 16; ++i) {
            int4 v = p[i];
            int j0 = tid * 64 + i * 4;
            int r;
            r = lcnt[v.x][tid]++; tok[r] = (j0+0) >> 1; rowidx[j0+0] = r;
            r = lcnt[v.y][tid]++; tok[r] = (j0+1) >> 1; rowidx[j0+1] = r;
            r = lcnt[v.z][tid]++; tok[r] = (j0+2) >> 1; rowidx[j0+2] = r;
            r = lcnt[v.w][tid]++; tok[r] = (j0+3) >> 1; rowidx[j0+3] = r;
        }
    }
}

// ---------------- transpose+convert: in [E][R][C] f32 -> out [E][C][R] bf16 ----------------
__global__ __launch_bounds__(256) void k_transpose(
    const float* __restrict__ in, __bf16* __restrict__ out, int R, int C)
{
    __shared__ float tile[64][65];
    const int e = blockIdx.z;
    const float* inp = in + (size_t)e * R * C;
    __bf16* outp = out + (size_t)e * R * C;
    const int r0 = blockIdx.x * 64, c0 = blockIdx.y * 64;
    const int c = threadIdx.x & 63, rr = threadIdx.x >> 6;
#pragma unroll
    for (int i = 0; i < 16; ++i) {
        int r = rr + i * 4;
        tile[r][c] = inp[(size_t)(r0 + r) * C + c0 + c];
    }
    __syncthreads();
#pragma unroll
    for (int i = 0; i < 16; ++i) {
        int cc = rr + i * 4;
        outp[(size_t)(c0 + cc) * R + r0 + c] = (__bf16)tile[c][cc];
    }
}

// ================= 256x256 / BK=64 4-phase-per-tile grouped GEMM =================
// 512 thr = 8 waves (2M x 4N). Per-wave out 128x64. Full-tile fragments in regs:
// av[8][2] (64 VGPR) + bv[4][2] (32 VGPR); acc[8][4] in AGPR.
// LDS 128 KiB: A[2buf][2half][128][64]bf16 @0, B same @65536.
// Swizzle: 16B chunk c of row R stored at c^(R&7) (pre-swizzled global src).
//
// ROUND-3/4 RESTRUCTURE (prefetch depth): all LDS reads of tile t complete in
// ph0-ph1 -> buffer regions free at ph2 -> stage tile t+2 at ph2 (A) / ph3 (B).
// One drain per tile: vmcnt(8) leaves tile t+2's 8 loads in flight; tile t+1's
// loads (issued during t-1's ph2-3) get a 4-6 phase lead before their drain.
// R4 fix: STAGE_A issued AFTER ph2's lgkmcnt(0) -> no WAR race between av<1>
// ds_reads (ph1) and the A-region overwrite (LDS-write of the gload return).

template<int BUF, int MIB>
__device__ __forceinline__ void rd_av(const char* sm, int wm, int r, int q, bf16x8 (&av)[8][2]) {
    const int rx = r & 7;
    const char* ab = sm + BUF*32768 + wm*16384 + r*128;
#pragma unroll
    for (int m2 = 0; m2 < 4; ++m2) {
        const char* rp = ab + (MIB*64 + m2*16)*128;
        av[MIB*4+m2][0] = *(const bf16x8*)(rp + (((0|q) ^ rx) << 4));
        av[MIB*4+m2][1] = *(const bf16x8*)(rp + (((4|q) ^ rx) << 4));
    }
}
template<int BUF, int NIB>
__device__ __forceinline__ void rd_bv(const char* sm, int wn, int r, int q, bf16x8 (&bv)[4][2]) {
    const int rx = r & 7;
    const char* bb = sm + 65536 + BUF*32768 + (wn>>1)*16384 + ((wn&1)*64 + NIB*32 + r)*128;
#pragma unroll
    for (int n2 = 0; n2 < 2; ++n2) {
        const char* rp = bb + n2*16*128;
        bv[NIB*2+n2][0] = *(const bf16x8*)(rp + (((0|q) ^ rx) << 4));
        bv[NIB*2+n2][1] = *(const bf16x8*)(rp + (((4|q) ^ rx) << 4));
    }
}
template<int MIB, int NIB>
__device__ __forceinline__ void mfma16(const bf16x8 (&av)[8][2], const bf16x8 (&bv)[4][2],
                                       f32x4 (&acc)[8][4]) {
#pragma unroll
    for (int m2 = 0; m2 < 4; ++m2)
#pragma unroll
        for (int n2 = 0; n2 < 2; ++n2) {
            f32x4 c = acc[MIB*4+m2][NIB*2+n2];
            c = __builtin_amdgcn_mfma_f32_16x16x32_bf16(av[MIB*4+m2][0], bv[NIB*2+n2][0], c, 0, 0, 0);
            c = __builtin_amdgcn_mfma_f32_16x16x32_bf16(av[MIB*4+m2][1], bv[NIB*2+n2][1], c, 0, 0, 0);
            acc[MIB*4+m2][NIB*2+n2] = c;
        }
}

#define BARR __builtin_amdgcn_s_barrier()
#define WLG0 asm volatile("s_waitcnt lgkmcnt(0)" ::: "memory")
#define WLG4 asm volatile("s_waitcnt lgkmcnt(4)" ::: "memory")
#define WLG8 asm volatile("s_waitcnt lgkmcnt(8)" ::: "memory")
#define WVM8 asm volatile("s_waitcnt vmcnt(8)" ::: "memory")
#define WVM0 asm volatile("s_waitcnt vmcnt(0)" ::: "memory")
#define P1 __builtin_amdgcn_s_setprio(1)
#define P0 __builtin_amdgcn_s_setprio(0)
#define STAGE_A(B_, H_, T_) { \
    gload_lds16(pA[H_][0] + (T_)*64, smem + (B_)*32768 + (H_)*16384 + wq); \
    gload_lds16(pA[H_][1] + (T_)*64, smem + (B_)*32768 + (H_)*16384 + 8192 + wq); }
#define STAGE_B(B_, H_, T_) { \
    gload_lds16(pB[H_][0] + (T_)*64, smem + 65536 + (B_)*32768 + (H_)*16384 + wq); \
    gload_lds16(pB[H_][1] + (T_)*64, smem + 65536 + (B_)*32768 + (H_)*16384 + 8192 + wq); }

// One K-tile = 4 phases. Reads: ph0 = av(MIB0) 8 + bv(NIB0) 4 + bv(NIB1) 4;
// ph1 = av(MIB1) 8 (all reads of this tile done by end-ph1). Stages (tile
// ST_ = T_+2, same buffer): ph2 = A halves (after lgkm drain), ph3 = B halves.
// DRAIN_ at end of ph3 (vmcnt(8): tile t+1 landed, tile t+2's 8 still flying).
#define TILE(BUF_, DOST_, ST_, DRAIN_) { \
    rd_av<BUF_,0>(smem, wm, r, q, av); rd_bv<BUF_,0>(smem, wn, r, q, bv); rd_bv<BUF_,1>(smem, wn, r, q, bv); \
    BARR; WLG4; P1; mfma16<0,0>(av, bv, acc); P0; BARR; \
    rd_av<BUF_,1>(smem, wm, r, q, av); \
    BARR; WLG8; P1; mfma16<0,1>(av, bv, acc); P0; BARR; \
    WLG0; \
    if (DOST_) { STAGE_A(BUF_, 0, ST_); STAGE_A(BUF_, 1, ST_); } \
    BARR; P1; mfma16<1,0>(av, bv, acc); P0; BARR; \
    if (DOST_) { STAGE_B(BUF_, 0, ST_); STAGE_B(BUF_, 1, ST_); } \
    BARR; P1; mfma16<1,1>(av, bv, acc); P0; DRAIN_; BARR; \
}

template<int KD, int NBLK, bool GATHER, bool RELU>
__global__ __launch_bounds__(512, 2) void k_gemm8(
    const __bf16* __restrict__ Asrc, const __bf16* __restrict__ WT,
    const float* __restrict__ bias, const int* __restrict__ tok,
    const int* __restrict__ mb2e, const int* __restrict__ mbrow0,
    const int* __restrict__ mbrowEnd, const int* __restrict__ mbTot,
    __bf16* __restrict__ outp)
{
    constexpr int NT = KD / 64;          // even, >= 4
    constexpr int NOUT = NBLK * 256;
    __shared__ __align__(16) char smem[131072];

    const int id   = blockIdx.x;
    const int xcd  = id & 7;
    const int j    = id >> 3;
    const int nblk = j % NBLK;
    const int mbi  = (j / NBLK) * 8 + xcd;
    if (mbi >= mbTot[0]) return;
    const int rowTot = mbTot[1];
    const int e    = mb2e[mbi];
    const int row0 = mbrow0[mbi];
    const int rEnd = mbrowEnd[mbi];
    const int n0   = nblk * 256;

    const int tid = threadIdx.x;
    const int w = tid >> 6, l = tid & 63;
    const int r = l & 15, q = l >> 4;
    const int wm = w >> 2, wn = w & 3;
    const int wq = w * 1024;

    // ---- staging source pointers (pre-swizzled global chunk) ----
    const int Rrow = l >> 3;                 // 0..7
    const int cg   = (l & 7) ^ Rrow;         // source 16B chunk (involution)
    const __bf16* Wb = WT + (size_t)e * ((size_t)NOUT * KD);
    const __bf16* pA[2][2]; const __bf16* pB[2][2];
#pragma unroll
    for (int h = 0; h < 2; ++h)
#pragma unroll
        for (int s = 0; s < 2; ++s) {
            int R  = s*64 + w*8 + Rrow;      // row within 256-tile half pair
            int ra = row0 + h*128 + R;
            ra = ra < rowTot ? ra : (rowTot - 1);   // clamp (pad-to-256 overhang)
            if (GATHER) pA[h][s] = Asrc + (size_t)tok[ra] * KD + cg*8;
            else        pA[h][s] = Asrc + (size_t)ra * KD + cg*8;
            pB[h][s] = Wb + (size_t)(n0 + h*128 + R) * KD + cg*8;
        }

    f32x4 acc[8][4];
#pragma unroll
    for (int mi = 0; mi < 8; ++mi)
#pragma unroll
        for (int ni = 0; ni < 4; ++ni) acc[mi][ni] = (f32x4){0.f, 0.f, 0.f, 0.f};

    bf16x8 av[8][2];      // full A tile fragments (this wave's 128 rows)
    bf16x8 bv[4][2];      // full B tile fragments (this wave's 64 cols)

    // ---- prologue: stage tile0 -> buf0, tile1 -> buf1; drain tile0, keep tile1 flying
    STAGE_A(0,0,0); STAGE_A(0,1,0); STAGE_B(0,0,0); STAGE_B(0,1,0);
    STAGE_A(1,0,1); STAGE_A(1,1,1); STAGE_B(1,0,1); STAGE_B(1,1,1);
    WVM8; BARR;

    // ---- main loop: tile t (buf t&1), staging tile t+2 into the same buffer ----
    for (int t0 = 0; t0 < NT - 2; t0 += 2) {
        TILE(0, true, t0+2, WVM8);
        TILE(1, true, t0+3, WVM8);
    }
    // tail: tiles NT-2, NT-1 (nothing left to stage)
    TILE(0, false, 0, WVM0);
    TILE(1, false, 0, (void)0);

    // ---- epilogue: bias (+relu), masked at expert-region end ----
    const float* be = bias + (size_t)e * NOUT;
    float bb4[4];
#pragma unroll
    for (int n2 = 0; n2 < 4; ++n2) bb4[n2] = be[n0 + wn*64 + n2*16 + r];
#pragma unroll
    for (int mi = 0; mi < 8; ++mi)
#pragma unroll
        for (int reg = 0; reg < 4; ++reg) {
            int row = row0 + wm*128 + mi*16 + q*4 + reg;
            if (row < rEnd) {
                __bf16* orow = outp + (size_t)row * NOUT + n0 + wn*64;
#pragma unroll
                for (int n2 = 0; n2 < 4; ++n2) {
                    float v = acc[mi][n2][reg] + bb4[n2];
                    if (RELU) v = fmaxf(v, 0.f);
                    orow[n2*16 + r] = (__bf16)v;
                }
            }
        }
}

// ---------------- combine: out[t] = s0*y[r0] + s1*y[r1] ----------------
__global__ __launch_bounds__(256) void k_combine(
    const __bf16* __restrict__ ybuf, const int* __restrict__ rowidx,
    const float* __restrict__ topk_s, float* __restrict__ out)
{
    const int t = blockIdx.x;
    const int d0 = threadIdx.x * 4;
    const int r0 = rowidx[t*2+0], r1 = rowidx[t*2+1];
    const float s0 = topk_s[t*2+0], s1 = topk_s[t*2+1];
    bf16x4 y0 = *(const bf16x4*)(ybuf + (size_t)r0 * D_DIM + d0);
    bf16x4 y1 = *(const bf16x4*)(ybuf + (size_t)r1 * D_DIM + d0);
    float4 o;
    o.x = s0 * (float)y0[0] + s1 * (float)y1[0];
    o.y = s0 * (float)y0[1] + s1 * (float)y1[1];
    o.z = s0 * (float)y0[2] + s1 * (float)y1[2];
    o.w = s0 * (float)y0[3] + s1 * (float)y1[3];
    *(float4*)(out + (size_t)t * D_DIM + d0) = o;
}

extern "C" void kernel_launch(void* const* d_in, const int* in_sizes, int n_in,
                              void* d_out, int out_size, void* d_ws, size_t ws_size,
                              hipStream_t stream) {
    const float* x  = (const float*)d_in[0];
    const float* Wg = (const float*)d_in[1];
    const float* W1 = (const float*)d_in[2];
    const float* b1 = (const float*)d_in[3];
    const float* W2 = (const float*)d_in[4];
    const float* b2 = (const float*)d_in[5];
    float* out = (float*)d_out;
    char* ws = (char*)d_ws;

    int*   mbTot  = (int*)  (ws + OFF_MBTOT);
    int*   mb2e   = (int*)  (ws + OFF_MB2E);
    int*   mbrow0 = (int*)  (ws + OFF_MBROW0);
    int*   mbrowEnd = (int*)(ws + OFF_MBEND);
    int*   topk_e = (int*)  (ws + OFF_TOPKE);
    float* topk_s = (float*)(ws + OFF_TOPKS);
    int*   tok    = (int*)  (ws + OFF_TOK);
    int*   rowidx = (int*)  (ws + OFF_ROWIDX);
    __bf16* xb   = (__bf16*)(ws + OFF_XB);
    __bf16* W1T  = (__bf16*)(ws + OFF_W1T);
    __bf16* W2T  = (__bf16*)(ws + OFF_W2T);
    __bf16* hbuf = (__bf16*)(ws + OFF_HBUF);
    __bf16* ybuf = (__bf16*)(ws + OFF_YBUF);

    // zero tok (pad rows -> tok=0). tables fully written by k_sort.
    hipMemsetAsync(ws + OFF_TOK, 0, MAX_ROWS * sizeof(int), stream);

    k_router_cvt<<<T_TOK/4, 256, 0, stream>>>(x, Wg, xb, topk_e, topk_s);
    k_sort      <<<1, 512, 0, stream>>>(topk_e, mbTot, mb2e, mbrow0, mbrowEnd, tok, rowidx);
    k_transpose <<<dim3(D_DIM/64, H_DIM/64, E_NUM), 256, 0, stream>>>(W1, W1T, D_DIM, H_DIM);
    k_transpose <<<dim3(H_DIM/64, D_DIM/64, E_NUM), 256, 0, stream>>>(W2, W2T, H_DIM, D_DIM);

    k_gemm8<D_DIM, H_DIM/256, true,  true ><<<MAX_MB256 * (H_DIM/256), 512, 0, stream>>>(
        xb, W1T, b1, tok, mb2e, mbrow0, mbrowEnd, mbTot, hbuf);
    k_gemm8<H_DIM, D_DIM/256, false, false><<<MAX_MB256 * (D_DIM/256), 512, 0, stream>>>(
        hbuf, W2T, b2, tok, mb2e, mbrow0, mbrowEnd, mbTot, ybuf);

    k_combine<<<T_TOK, 256, 0, stream>>>(ybuf, rowidx, topk_s, out);
}

// Round 5
// 417.456 us; speedup vs baseline: 1.7569x; 1.7569x over previous
//
#include <hip/hip_runtime.h>
#include <hip/hip_bf16.h>

typedef __bf16 bf16x8 __attribute__((ext_vector_type(8)));
typedef __bf16 bf16x4 __attribute__((ext_vector_type(4)));
typedef float  f32x4  __attribute__((ext_vector_type(4)));

#define T_TOK    8192
#define D_DIM    1024
#define H_DIM    2048
#define E_NUM    8
#define MAX_MB   136      // 17*8 (128-row blocks)
#define MAX_ROWS 17408    // 136*128

// ---- workspace layout (bytes) ----
#define OFF_MBTOT   512
#define OFF_MB2E    1024
#define OFF_MBROW0  2048
#define OFF_TOPKE   4096            // 16384 ints  -> ends 69632
#define OFF_TOPKS   69632           // 16384 float -> ends 135168
#define OFF_TOK     135168          // 17408 ints  -> ends 204800
#define OFF_ROWIDX  204800          // 16384 ints  -> ends 270336
#define OFF_XB      (1u<<20)                    // 8192*1024*2  = 16 MiB
#define OFF_W1T     (18u*1024*1024)             // 8*2048*1024*2 = 32 MiB -> ends 50 MiB
#define OFF_W2T     (50u*1024*1024)             // 8*1024*2048*2 = 32 MiB -> ends 82 MiB
#define OFF_HBUF    (82u*1024*1024)             // 17408*2048*2  = 68 MiB -> ends 150 MiB
#define OFF_YBUF    OFF_XB                      // ybuf overlaid on xb+W1T (dead after gemm1)

__device__ __forceinline__ void gload_lds16(const void* g, void* l) {
    __builtin_amdgcn_global_load_lds(
        (const __attribute__((address_space(1))) void*)g,
        (__attribute__((address_space(3))) void*)l, 16, 0, 0);
}

// ---------------- fused router (+ fp32->bf16 convert of x), NO atomics ----------------
__global__ __launch_bounds__(256) void k_router_cvt(
    const float* __restrict__ x, const float* __restrict__ Wg,
    __bf16* __restrict__ xb, int* __restrict__ topk_e, float* __restrict__ topk_s)
{
    __shared__ float wgT[E_NUM][1032];   // padded stride
    const int tid = threadIdx.x;
#pragma unroll
    for (int i = 0; i < 32; ++i) {
        int f = tid + i * 256;           // coalesced read of Wg[1024][8]
        wgT[f & 7][f >> 3] = Wg[f];
    }
    __syncthreads();

    const int wave = tid >> 6, lane = tid & 63;
    const int t = blockIdx.x * 4 + wave;
    const float* xr = x + (size_t)t * D_DIM;
    __bf16* xbr = xb + (size_t)t * D_DIM;

    float acc[E_NUM];
#pragma unroll
    for (int e = 0; e < E_NUM; ++e) acc[e] = 0.f;

#pragma unroll
    for (int j = 0; j < 4; ++j) {
        const int d0 = lane * 4 + j * 256;
        float4 xv = *(const float4*)(xr + d0);
        bf16x4 o = { (__bf16)xv.x, (__bf16)xv.y, (__bf16)xv.z, (__bf16)xv.w };
        *(bf16x4*)(xbr + d0) = o;
#pragma unroll
        for (int e = 0; e < E_NUM; ++e) {
            float4 wv = *(const float4*)&wgT[e][d0];
            acc[e] += xv.x * wv.x + xv.y * wv.y + xv.z * wv.z + xv.w * wv.w;
        }
    }
#pragma unroll
    for (int off = 32; off >= 1; off >>= 1)
#pragma unroll
        for (int e = 0; e < E_NUM; ++e) acc[e] += __shfl_xor(acc[e], off, 64);

    if (lane == 0) {
        int e0 = 0; float v0 = acc[0];
#pragma unroll
        for (int e = 1; e < E_NUM; ++e) if (acc[e] > v0) { v0 = acc[e]; e0 = e; }
        int e1 = -1; float v1 = -1e30f;
#pragma unroll
        for (int e = 0; e < E_NUM; ++e) if (e != e0 && acc[e] > v1) { v1 = acc[e]; e1 = e; }
        float s0 = 1.f / (1.f + __expf(v1 - v0));  // renormalized top-2 softmax
        float s1 = 1.f - s0;
        topk_e[t*2+0] = e0; topk_e[t*2+1] = e1;
        topk_s[t*2+0] = s0; topk_s[t*2+1] = s1;
    }
}

// ---------------- single-block counting sort (round-0 proven version) ----------------
#define SORT_T 256
__global__ __launch_bounds__(512) void k_sort(
    const int* __restrict__ topk_e,
    int* __restrict__ mbTot, int* __restrict__ mb2e, int* __restrict__ mbrow0,
    int* __restrict__ tok, int* __restrict__ rowidx)
{
    __shared__ int lcnt[E_NUM][SORT_T];
    __shared__ int base[E_NUM];
    __shared__ int etot[E_NUM];
    const int tid = threadIdx.x;

    if (tid < SORT_T) {
#pragma unroll
        for (int e = 0; e < E_NUM; ++e) lcnt[e][tid] = 0;
    }
    __syncthreads();

    if (tid < SORT_T) {
        const int4* p = (const int4*)(topk_e + tid * 64);
#pragma unroll
        for (int i = 0; i < 16; ++i) {
            int4 v = p[i];
            lcnt[v.x][tid]++; lcnt[v.y][tid]++; lcnt[v.z][tid]++; lcnt[v.w][tid]++;
        }
    }
    __syncthreads();

    {
        const int w = tid >> 6, l = tid & 63;
        int v0 = lcnt[w][l*4+0], v1 = lcnt[w][l*4+1], v2 = lcnt[w][l*4+2], v3 = lcnt[w][l*4+3];
        int s = v0 + v1 + v2 + v3;
        int inc = s;
#pragma unroll
        for (int off = 1; off < 64; off <<= 1) {
            int o = __shfl_up(inc, off, 64);
            if (l >= off) inc += o;
        }
        int exc = inc - s;
        lcnt[w][l*4+0] = exc;
        lcnt[w][l*4+1] = exc + v0;
        lcnt[w][l*4+2] = exc + v0 + v1;
        lcnt[w][l*4+3] = exc + v0 + v1 + v2;
        if (l == 63) etot[w] = inc;
    }
    __syncthreads();

    if (tid == 0) {
        int row = 0, mb = 0;
        for (int e = 0; e < E_NUM; ++e) {
            base[e] = row;
            int nb = (etot[e] + 127) >> 7;
            for (int b = 0; b < nb; ++b) { mb2e[mb] = e; mbrow0[mb] = row + b*128; ++mb; }
            row += nb * 128;
        }
        mbTot[0] = mb;
    }
    __syncthreads();

    if (tid < SORT_T) {
#pragma unroll
        for (int e = 0; e < E_NUM; ++e) lcnt[e][tid] += base[e];
        const int4* p = (const int4*)(topk_e + tid * 64);
#pragma unroll
        for (int i = 0; i < 16; ++i) {
            int4 v = p[i];
            int j0 = tid * 64 + i * 4;
            int r;
            r = lcnt[v.x][tid]++; tok[r] = (j0+0) >> 1; rowidx[j0+0] = r;
            r = lcnt[v.y][tid]++; tok[r] = (j0+1) >> 1; rowidx[j0+1] = r;
            r = lcnt[v.z][tid]++; tok[r] = (j0+2) >> 1; rowidx[j0+2] = r;
            r = lcnt[v.w][tid]++; tok[r] = (j0+3) >> 1; rowidx[j0+3] = r;
        }
    }
}

// ---------------- transpose+convert: in [E][R][C] f32 -> out [E][C][R] bf16 ----------------
__global__ __launch_bounds__(256) void k_transpose(
    const float* __restrict__ in, __bf16* __restrict__ out, int R, int C)
{
    __shared__ float tile[64][65];
    const int e = blockIdx.z;
    const float* inp = in + (size_t)e * R * C;
    __bf16* outp = out + (size_t)e * R * C;
    const int r0 = blockIdx.x * 64, c0 = blockIdx.y * 64;
    const int c = threadIdx.x & 63, rr = threadIdx.x >> 6;
#pragma unroll
    for (int i = 0; i < 16; ++i) {
        int r = rr + i * 4;
        tile[r][c] = inp[(size_t)(r0 + r) * C + c0 + c];
    }
    __syncthreads();
#pragma unroll
    for (int i = 0; i < 16; ++i) {
        int cc = rr + i * 4;
        outp[(size_t)(c0 + cc) * R + r0 + c] = (__bf16)tile[c][cc];
    }
}

// ============== 128x256 / BK=32, 3-deep pipelined grouped GEMM ==============
// 512 thr = 8 waves (2M x 4N); wave tile 64x64; acc[4][4] f32x4 (64 regs).
// LDS 72 KiB: A[3][128][32]bf16 (24K) + B[3][256][32] (48K) -> 2 blocks/CU (TLP!).
// Linear layout: a wave's 64-lane (r,q) ds_read_b128 covers a dense contiguous
// 1 KiB (16 rows x 4 chunks) -> zero bank conflicts, no swizzle needed.
// Pipeline: tile t+2 staged while computing tile t (lead ~2 K-tiles > HBM
// latency); per-tile drain vmcnt(3) keeps t+2's 3 loads in flight, never 0.

#define LDSB_OFF 24576

#define BARR __builtin_amdgcn_s_barrier()
#define WVM3 asm volatile("s_waitcnt vmcnt(3)" ::: "memory")
#define WVM0 asm volatile("s_waitcnt vmcnt(0)" ::: "memory")
#define P1 __builtin_amdgcn_s_setprio(1)
#define P0 __builtin_amdgcn_s_setprio(0)

// stage tile T_ into buffer slot BS_ (runtime ints). 3 gloads/thread.
#define STAGE(BS_, T_) { \
    gload_lds16(pA  + (T_)*32, smem + (BS_)*8192 + wq); \
    gload_lds16(pB0 + (T_)*32, smem + LDSB_OFF + (BS_)*16384 + wq); \
    gload_lds16(pB1 + (T_)*32, smem + LDSB_OFF + (BS_)*16384 + 8192 + wq); }

#define RD_TILE(BS_) { \
    const char* ba = smem + (BS_)*8192; \
    const char* bb = smem + LDSB_OFF + (BS_)*16384; \
    av[0] = *(const bf16x8*)(ba + (wm*64 +  0 + r)*64 + q*16); \
    av[1] = *(const bf16x8*)(ba + (wm*64 + 16 + r)*64 + q*16); \
    av[2] = *(const bf16x8*)(ba + (wm*64 + 32 + r)*64 + q*16); \
    av[3] = *(const bf16x8*)(ba + (wm*64 + 48 + r)*64 + q*16); \
    bv[0] = *(const bf16x8*)(bb + (wn*64 +  0 + r)*64 + q*16); \
    bv[1] = *(const bf16x8*)(bb + (wn*64 + 16 + r)*64 + q*16); \
    bv[2] = *(const bf16x8*)(bb + (wn*64 + 32 + r)*64 + q*16); \
    bv[3] = *(const bf16x8*)(bb + (wn*64 + 48 + r)*64 + q*16); }

#define MFMA16 { \
    _Pragma("unroll") \
    for (int mi = 0; mi < 4; ++mi) \
    _Pragma("unroll") \
    for (int ni = 0; ni < 4; ++ni) \
        acc[mi][ni] = __builtin_amdgcn_mfma_f32_16x16x32_bf16(av[mi], bv[ni], acc[mi][ni], 0, 0, 0); }

template<int KD, int NBLK, bool GATHER, bool RELU>
__global__ __launch_bounds__(512, 4) void k_gemm(
    const __bf16* __restrict__ Asrc, const __bf16* __restrict__ WT,
    const float* __restrict__ bias, const int* __restrict__ tok,
    const int* __restrict__ mb2e, const int* __restrict__ mbrow0,
    const int* __restrict__ mbTot, __bf16* __restrict__ outp)
{
    constexpr int NT = KD / 32;          // 32 (gemm1) or 64 (gemm2)
    constexpr int NOUT = NBLK * 256;
    __shared__ __align__(16) char smem[73728];

    const int id   = blockIdx.x;
    const int xcd  = id & 7;
    const int j    = id >> 3;
    const int nblk = j % NBLK;
    const int mbi  = (j / NBLK) * 8 + xcd;
    if (mbi >= *mbTot) return;
    const int e    = mb2e[mbi];
    const int row0 = mbrow0[mbi];
    const int n0   = nblk * 256;

    const int tid = threadIdx.x;
    const int w = tid >> 6, l = tid & 63;
    const int r = l & 15, q = l >> 4;
    const int wm = w >> 2, wn = w & 3;       // 2M x 4N wave grid
    const int wq = w * 1024;                  // wave-uniform LDS stage base

    // ---- staging source pointers (linear; 1 A-chunk + 2 B-chunks per thread) ----
    const __bf16* Wb = WT + (size_t)e * ((size_t)NOUT * KD);
    const __bf16* pA;
    {
        int ar = row0 + (tid >> 2);           // 128 rows, 4 chunks each
        pA = GATHER ? Asrc + (size_t)tok[ar] * KD + (tid & 3) * 8
                    : Asrc + (size_t)ar * KD + (tid & 3) * 8;
    }
    const __bf16* pB0 = Wb + (size_t)(n0 + (tid >> 2)) * KD + (tid & 3) * 8;
    const __bf16* pB1 = Wb + (size_t)(n0 + 128 + (tid >> 2)) * KD + (tid & 3) * 8;

    f32x4 acc[4][4];
#pragma unroll
    for (int mi = 0; mi < 4; ++mi)
#pragma unroll
        for (int ni = 0; ni < 4; ++ni) acc[mi][ni] = (f32x4){0.f, 0.f, 0.f, 0.f};

    bf16x8 av[4], bv[4];

    // ---- prologue: stage tiles 0,1; drain tile0 (tile1's 3 stay in flight) ----
    STAGE(0, 0); STAGE(1, 1);
    WVM3; BARR;

    // ---- main loop: compute tile t from buf bs, stage t+2 into freed buf ----
    int bs = 0, bs2 = 2;                      // bs2 = (bs+2)%3 = buffer of t-1 (freed)
    for (int t = 0; t < NT - 2; ++t) {
        RD_TILE(bs);
        STAGE(bs2, t + 2);
        P1; MFMA16; P0;
        WVM3;                                  // tile t+1 landed; t+2's 3 in flight
        BARR;
        int nb = (bs == 2) ? 0 : bs + 1;
        bs2 = bs; bs = nb;
    }
    // tile NT-2: no stage; drain tile NT-1 fully
    RD_TILE(bs);
    P1; MFMA16; P0;
    WVM0; BARR;
    bs = (bs == 2) ? 0 : bs + 1;
    // tile NT-1
    RD_TILE(bs);
    P1; MFMA16; P0;

    // ---- epilogue: bias (+relu); pad rows land in pad region (harmless) ----
    const float* be = bias + (size_t)e * NOUT;
    float bb4[4];
#pragma unroll
    for (int ni = 0; ni < 4; ++ni) bb4[ni] = be[n0 + wn*64 + ni*16 + r];
#pragma unroll
    for (int mi = 0; mi < 4; ++mi)
#pragma unroll
        for (int reg = 0; reg < 4; ++reg) {
            int row = row0 + wm*64 + mi*16 + q*4 + reg;
            __bf16* orow = outp + (size_t)row * NOUT + n0 + wn*64;
#pragma unroll
            for (int ni = 0; ni < 4; ++ni) {
                float v = acc[mi][ni][reg] + bb4[ni];
                if (RELU) v = fmaxf(v, 0.f);
                orow[ni*16 + r] = (__bf16)v;
            }
        }
}

// ---------------- combine: out[t] = s0*y[r0] + s1*y[r1] ----------------
__global__ __launch_bounds__(256) void k_combine(
    const __bf16* __restrict__ ybuf, const int* __restrict__ rowidx,
    const float* __restrict__ topk_s, float* __restrict__ out)
{
    const int t = blockIdx.x;
    const int d0 = threadIdx.x * 4;
    const int r0 = rowidx[t*2+0], r1 = rowidx[t*2+1];
    const float s0 = topk_s[t*2+0], s1 = topk_s[t*2+1];
    bf16x4 y0 = *(const bf16x4*)(ybuf + (size_t)r0 * D_DIM + d0);
    bf16x4 y1 = *(const bf16x4*)(ybuf + (size_t)r1 * D_DIM + d0);
    float4 o;
    o.x = s0 * (float)y0[0] + s1 * (float)y1[0];
    o.y = s0 * (float)y0[1] + s1 * (float)y1[1];
    o.z = s0 * (float)y0[2] + s1 * (float)y1[2];
    o.w = s0 * (float)y0[3] + s1 * (float)y1[3];
    *(float4*)(out + (size_t)t * D_DIM + d0) = o;
}

extern "C" void kernel_launch(void* const* d_in, const int* in_sizes, int n_in,
                              void* d_out, int out_size, void* d_ws, size_t ws_size,
                              hipStream_t stream) {
    const float* x  = (const float*)d_in[0];
    const float* Wg = (const float*)d_in[1];
    const float* W1 = (const float*)d_in[2];
    const float* b1 = (const float*)d_in[3];
    const float* W2 = (const float*)d_in[4];
    const float* b2 = (const float*)d_in[5];
    float* out = (float*)d_out;
    char* ws = (char*)d_ws;

    int*   mbTot  = (int*)  (ws + OFF_MBTOT);
    int*   mb2e   = (int*)  (ws + OFF_MB2E);
    int*   mbrow0 = (int*)  (ws + OFF_MBROW0);
    int*   topk_e = (int*)  (ws + OFF_TOPKE);
    float* topk_s = (float*)(ws + OFF_TOPKS);
    int*   tok    = (int*)  (ws + OFF_TOK);
    int*   rowidx = (int*)  (ws + OFF_ROWIDX);
    __bf16* xb   = (__bf16*)(ws + OFF_XB);
    __bf16* W1T  = (__bf16*)(ws + OFF_W1T);
    __bf16* W2T  = (__bf16*)(ws + OFF_W2T);
    __bf16* hbuf = (__bf16*)(ws + OFF_HBUF);
    __bf16* ybuf = (__bf16*)(ws + OFF_YBUF);

    // zero tok (pad rows -> tok=0). tables fully written by k_sort.
    hipMemsetAsync(ws + OFF_TOK, 0, MAX_ROWS * sizeof(int), stream);

    k_router_cvt<<<T_TOK/4, 256, 0, stream>>>(x, Wg, xb, topk_e, topk_s);
    k_sort      <<<1, 512, 0, stream>>>(topk_e, mbTot, mb2e, mbrow0, tok, rowidx);
    k_transpose <<<dim3(D_DIM/64, H_DIM/64, E_NUM), 256, 0, stream>>>(W1, W1T, D_DIM, H_DIM);
    k_transpose <<<dim3(H_DIM/64, D_DIM/64, E_NUM), 256, 0, stream>>>(W2, W2T, H_DIM, D_DIM);

    k_gemm<D_DIM, 8, true,  true ><<<MAX_MB * 8, 512, 0, stream>>>(
        xb, W1T, b1, tok, mb2e, mbrow0, mbTot, hbuf);
    k_gemm<H_DIM, 4, false, false><<<MAX_MB * 4, 512, 0, stream>>>(
        hbuf, W2T, b2, tok, mb2e, mbrow0, mbTot, ybuf);

    k_combine<<<T_TOK, 256, 0, stream>>>(ybuf, rowidx, topk_s, out);
}

// Round 6
// 414.073 us; speedup vs baseline: 1.7712x; 1.0082x over previous
//
#include <hip/hip_runtime.h>
#include <hip/hip_bf16.h>

typedef __bf16 bf16x8 __attribute__((ext_vector_type(8)));
typedef __bf16 bf16x4 __attribute__((ext_vector_type(4)));
typedef float  f32x4  __attribute__((ext_vector_type(4)));

#define T_TOK    8192
#define D_DIM    1024
#define H_DIM    2048
#define E_NUM    8
#define MAX_MB   136      // 17*8 (128-row blocks)
#define MAX_ROWS 17408    // 136*128

// ---- workspace layout (bytes) ----
#define OFF_MBTOT   512
#define OFF_MB2E    1024
#define OFF_MBROW0  2048
#define OFF_TOPKE   4096            // 16384 ints  -> ends 69632
#define OFF_TOPKS   69632           // 16384 float -> ends 135168
#define OFF_TOK     135168          // 17408 ints  -> ends 204800
#define OFF_ROWIDX  204800          // 16384 ints  -> ends 270336
#define OFF_XB      (1u<<20)                    // 8192*1024*2  = 16 MiB
#define OFF_W1T     (18u*1024*1024)             // 8*2048*1024*2 = 32 MiB -> ends 50 MiB
#define OFF_W2T     (50u*1024*1024)             // 8*1024*2048*2 = 32 MiB -> ends 82 MiB
#define OFF_HBUF    (82u*1024*1024)             // 17408*2048*2  = 68 MiB -> ends 150 MiB
#define OFF_YBUF    OFF_XB                      // ybuf overlaid on xb+W1T (dead after gemm1)

__device__ __forceinline__ void gload_lds16(const void* g, void* l) {
    __builtin_amdgcn_global_load_lds(
        (const __attribute__((address_space(1))) void*)g,
        (__attribute__((address_space(3))) void*)l, 16, 0, 0);
}

// ---------------- fused router (+ fp32->bf16 convert of x), NO atomics ----------------
__global__ __launch_bounds__(256) void k_router_cvt(
    const float* __restrict__ x, const float* __restrict__ Wg,
    __bf16* __restrict__ xb, int* __restrict__ topk_e, float* __restrict__ topk_s)
{
    __shared__ float wgT[E_NUM][1032];   // padded stride
    const int tid = threadIdx.x;
#pragma unroll
    for (int i = 0; i < 32; ++i) {
        int f = tid + i * 256;           // coalesced read of Wg[1024][8]
        wgT[f & 7][f >> 3] = Wg[f];
    }
    __syncthreads();

    const int wave = tid >> 6, lane = tid & 63;
    const int t = blockIdx.x * 4 + wave;
    const float* xr = x + (size_t)t * D_DIM;
    __bf16* xbr = xb + (size_t)t * D_DIM;

    float acc[E_NUM];
#pragma unroll
    for (int e = 0; e < E_NUM; ++e) acc[e] = 0.f;

#pragma unroll
    for (int j = 0; j < 4; ++j) {
        const int d0 = lane * 4 + j * 256;
        float4 xv = *(const float4*)(xr + d0);
        bf16x4 o = { (__bf16)xv.x, (__bf16)xv.y, (__bf16)xv.z, (__bf16)xv.w };
        *(bf16x4*)(xbr + d0) = o;
#pragma unroll
        for (int e = 0; e < E_NUM; ++e) {
            float4 wv = *(const float4*)&wgT[e][d0];
            acc[e] += xv.x * wv.x + xv.y * wv.y + xv.z * wv.z + xv.w * wv.w;
        }
    }
#pragma unroll
    for (int off = 32; off >= 1; off >>= 1)
#pragma unroll
        for (int e = 0; e < E_NUM; ++e) acc[e] += __shfl_xor(acc[e], off, 64);

    if (lane == 0) {
        int e0 = 0; float v0 = acc[0];
#pragma unroll
        for (int e = 1; e < E_NUM; ++e) if (acc[e] > v0) { v0 = acc[e]; e0 = e; }
        int e1 = -1; float v1 = -1e30f;
#pragma unroll
        for (int e = 0; e < E_NUM; ++e) if (e != e0 && acc[e] > v1) { v1 = acc[e]; e1 = e; }
        float s0 = 1.f / (1.f + __expf(v1 - v0));  // renormalized top-2 softmax
        float s1 = 1.f - s0;
        topk_e[t*2+0] = e0; topk_e[t*2+1] = e1;
        topk_s[t*2+0] = s0; topk_s[t*2+1] = s1;
    }
}

// ---------------- single-block counting sort (round-0 proven version) ----------------
#define SORT_T 256
__global__ __launch_bounds__(512) void k_sort(
    const int* __restrict__ topk_e,
    int* __restrict__ mbTot, int* __restrict__ mb2e, int* __restrict__ mbrow0,
    int* __restrict__ tok, int* __restrict__ rowidx)
{
    __shared__ int lcnt[E_NUM][SORT_T];
    __shared__ int base[E_NUM];
    __shared__ int etot[E_NUM];
    const int tid = threadIdx.x;

    if (tid < SORT_T) {
#pragma unroll
        for (int e = 0; e < E_NUM; ++e) lcnt[e][tid] = 0;
    }
    __syncthreads();

    if (tid < SORT_T) {
        const int4* p = (const int4*)(topk_e + tid * 64);
#pragma unroll
        for (int i = 0; i < 16; ++i) {
            int4 v = p[i];
            lcnt[v.x][tid]++; lcnt[v.y][tid]++; lcnt[v.z][tid]++; lcnt[v.w][tid]++;
        }
    }
    __syncthreads();

    {
        const int w = tid >> 6, l = tid & 63;
        int v0 = lcnt[w][l*4+0], v1 = lcnt[w][l*4+1], v2 = lcnt[w][l*4+2], v3 = lcnt[w][l*4+3];
        int s = v0 + v1 + v2 + v3;
        int inc = s;
#pragma unroll
        for (int off = 1; off < 64; off <<= 1) {
            int o = __shfl_up(inc, off, 64);
            if (l >= off) inc += o;
        }
        int exc = inc - s;
        lcnt[w][l*4+0] = exc;
        lcnt[w][l*4+1] = exc + v0;
        lcnt[w][l*4+2] = exc + v0 + v1;
        lcnt[w][l*4+3] = exc + v0 + v1 + v2;
        if (l == 63) etot[w] = inc;
    }
    __syncthreads();

    if (tid == 0) {
        int row = 0, mb = 0;
        for (int e = 0; e < E_NUM; ++e) {
            base[e] = row;
            int nb = (etot[e] + 127) >> 7;
            for (int b = 0; b < nb; ++b) { mb2e[mb] = e; mbrow0[mb] = row + b*128; ++mb; }
            row += nb * 128;
        }
        mbTot[0] = mb;
    }
    __syncthreads();

    if (tid < SORT_T) {
#pragma unroll
        for (int e = 0; e < E_NUM; ++e) lcnt[e][tid] += base[e];
        const int4* p = (const int4*)(topk_e + tid * 64);
#pragma unroll
        for (int i = 0; i < 16; ++i) {
            int4 v = p[i];
            int j0 = tid * 64 + i * 4;
            int r;
            r = lcnt[v.x][tid]++; tok[r] = (j0+0) >> 1; rowidx[j0+0] = r;
            r = lcnt[v.y][tid]++; tok[r] = (j0+1) >> 1; rowidx[j0+1] = r;
            r = lcnt[v.z][tid]++; tok[r] = (j0+2) >> 1; rowidx[j0+2] = r;
            r = lcnt[v.w][tid]++; tok[r] = (j0+3) >> 1; rowidx[j0+3] = r;
        }
    }
}

// ---------------- transpose+convert: in [E][R][C] f32 -> out [E][C][R] bf16 ----------------
__global__ __launch_bounds__(256) void k_transpose(
    const float* __restrict__ in, __bf16* __restrict__ out, int R, int C)
{
    __shared__ float tile[64][65];
    const int e = blockIdx.z;
    const float* inp = in + (size_t)e * R * C;
    __bf16* outp = out + (size_t)e * R * C;
    const int r0 = blockIdx.x * 64, c0 = blockIdx.y * 64;
    const int c = threadIdx.x & 63, rr = threadIdx.x >> 6;
#pragma unroll
    for (int i = 0; i < 16; ++i) {
        int r = rr + i * 4;
        tile[r][c] = inp[(size_t)(r0 + r) * C + c0 + c];
    }
    __syncthreads();
#pragma unroll
    for (int i = 0; i < 16; ++i) {
        int cc = rr + i * 4;
        outp[(size_t)(c0 + cc) * R + r0 + c] = (__bf16)tile[c][cc];
    }
}

// ============== 128x256 / BK=32, 3-deep pipelined grouped GEMM ==============
// 512 thr = 8 waves (2M x 4N); wave tile 64x64; acc[4][4] f32x4 (64 AGPRs).
// LDS 72 KiB: A[3][128][32]bf16 (24K) + B[3][256][32] (48K) -> 2 blocks/CU.
// ROUND-6: restore round-0's PROVEN chunk swizzle (linear q*16 was an 8-way
// bank conflict, 8.65M SQ_LDS_BANK_CONFLICT): global source chunk
// cg = (tid&3) ^ ((tid>>3)&3)  (row = tid>>2), LDS dest linear; read chunk
// qx = (q ^ ((r>>1)&3))*16. Same involution both sides -> 0 conflicts (r0-proven).
// Pipeline: tile t+2 staged while computing tile t; drain vmcnt(3), never 0.

#define LDSB_OFF 24576

#define BARR __builtin_amdgcn_s_barrier()
#define WVM3 asm volatile("s_waitcnt vmcnt(3)" ::: "memory")
#define WVM0 asm volatile("s_waitcnt vmcnt(0)" ::: "memory")
#define P1 __builtin_amdgcn_s_setprio(1)
#define P0 __builtin_amdgcn_s_setprio(0)

// stage tile T_ into buffer slot BS_ (runtime ints). 3 gloads/thread.
#define STAGE(BS_, T_) { \
    gload_lds16(pA  + (T_)*32, smem + (BS_)*8192 + wq); \
    gload_lds16(pB0 + (T_)*32, smem + LDSB_OFF + (BS_)*16384 + wq); \
    gload_lds16(pB1 + (T_)*32, smem + LDSB_OFF + (BS_)*16384 + 8192 + wq); }

#define RD_TILE(BS_) { \
    const char* ba = smem + (BS_)*8192; \
    const char* bb = smem + LDSB_OFF + (BS_)*16384; \
    av[0] = *(const bf16x8*)(ba + (wm*64 +  0 + r)*64 + qx); \
    av[1] = *(const bf16x8*)(ba + (wm*64 + 16 + r)*64 + qx); \
    av[2] = *(const bf16x8*)(ba + (wm*64 + 32 + r)*64 + qx); \
    av[3] = *(const bf16x8*)(ba + (wm*64 + 48 + r)*64 + qx); \
    bv[0] = *(const bf16x8*)(bb + (wn*64 +  0 + r)*64 + qx); \
    bv[1] = *(const bf16x8*)(bb + (wn*64 + 16 + r)*64 + qx); \
    bv[2] = *(const bf16x8*)(bb + (wn*64 + 32 + r)*64 + qx); \
    bv[3] = *(const bf16x8*)(bb + (wn*64 + 48 + r)*64 + qx); }

#define MFMA16 { \
    _Pragma("unroll") \
    for (int mi = 0; mi < 4; ++mi) \
    _Pragma("unroll") \
    for (int ni = 0; ni < 4; ++ni) \
        acc[mi][ni] = __builtin_amdgcn_mfma_f32_16x16x32_bf16(av[mi], bv[ni], acc[mi][ni], 0, 0, 0); }

template<int KD, int NBLK, bool GATHER, bool RELU>
__global__ __launch_bounds__(512, 4) void k_gemm(
    const __bf16* __restrict__ Asrc, const __bf16* __restrict__ WT,
    const float* __restrict__ bias, const int* __restrict__ tok,
    const int* __restrict__ mb2e, const int* __restrict__ mbrow0,
    const int* __restrict__ mbTot, __bf16* __restrict__ outp)
{
    constexpr int NT = KD / 32;          // 32 (gemm1) or 64 (gemm2)
    constexpr int NOUT = NBLK * 256;
    __shared__ __align__(16) char smem[73728];

    const int id   = blockIdx.x;
    const int xcd  = id & 7;
    const int j    = id >> 3;
    const int nblk = j % NBLK;
    const int mbi  = (j / NBLK) * 8 + xcd;
    if (mbi >= *mbTot) return;
    const int e    = mb2e[mbi];
    const int row0 = mbrow0[mbi];
    const int n0   = nblk * 256;

    const int tid = threadIdx.x;
    const int w = tid >> 6, l = tid & 63;
    const int r = l & 15, q = l >> 4;
    const int wm = w >> 2, wn = w & 3;       // 2M x 4N wave grid
    const int wq = w * 1024;                  // wave-uniform LDS stage base
    const int qx = (q ^ ((r >> 1) & 3)) * 16; // swizzled read chunk (r0-proven)

    // ---- staging source pointers: pre-swizzled global chunk (involution) ----
    const int cg = (tid & 3) ^ ((tid >> 3) & 3);  // row = tid>>2 -> (row>>1)&3 = (tid>>3)&3
    const __bf16* Wb = WT + (size_t)e * ((size_t)NOUT * KD);
    const __bf16* pA;
    {
        int ar = row0 + (tid >> 2);           // 128 rows, 4 chunks each
        pA = GATHER ? Asrc + (size_t)tok[ar] * KD + cg * 8
                    : Asrc + (size_t)ar * KD + cg * 8;
    }
    const __bf16* pB0 = Wb + (size_t)(n0 + (tid >> 2)) * KD + cg * 8;
    const __bf16* pB1 = Wb + (size_t)(n0 + 128 + (tid >> 2)) * KD + cg * 8;

    f32x4 acc[4][4];
#pragma unroll
    for (int mi = 0; mi < 4; ++mi)
#pragma unroll
        for (int ni = 0; ni < 4; ++ni) acc[mi][ni] = (f32x4){0.f, 0.f, 0.f, 0.f};

    bf16x8 av[4], bv[4];

    // ---- prologue: stage tiles 0,1; drain tile0 (tile1's 3 stay in flight) ----
    STAGE(0, 0); STAGE(1, 1);
    WVM3; BARR;

    // ---- main loop: compute tile t from buf bs, stage t+2 into freed buf ----
    int bs = 0, bs2 = 2;                      // bs2 = buffer of t-1 (freed)
    for (int t = 0; t < NT - 2; ++t) {
        RD_TILE(bs);
        STAGE(bs2, t + 2);
        P1; MFMA16; P0;
        WVM3;                                  // tile t+1 landed; t+2's 3 in flight
        BARR;
        int nb = (bs == 2) ? 0 : bs + 1;
        bs2 = bs; bs = nb;
    }
    // tile NT-2: no stage; drain tile NT-1 fully
    RD_TILE(bs);
    P1; MFMA16; P0;
    WVM0; BARR;
    bs = (bs == 2) ? 0 : bs + 1;
    // tile NT-1
    RD_TILE(bs);
    P1; MFMA16; P0;

    // ---- epilogue: bias (+relu); pad rows land in pad region (harmless) ----
    const float* be = bias + (size_t)e * NOUT;
    float bb4[4];
#pragma unroll
    for (int ni = 0; ni < 4; ++ni) bb4[ni] = be[n0 + wn*64 + ni*16 + r];
#pragma unroll
    for (int mi = 0; mi < 4; ++mi)
#pragma unroll
        for (int reg = 0; reg < 4; ++reg) {
            int row = row0 + wm*64 + mi*16 + q*4 + reg;
            __bf16* orow = outp + (size_t)row * NOUT + n0 + wn*64;
#pragma unroll
            for (int ni = 0; ni < 4; ++ni) {
                float v = acc[mi][ni][reg] + bb4[ni];
                if (RELU) v = fmaxf(v, 0.f);
                orow[ni*16 + r] = (__bf16)v;
            }
        }
}

// ---------------- combine: out[t] = s0*y[r0] + s1*y[r1] ----------------
__global__ __launch_bounds__(256) void k_combine(
    const __bf16* __restrict__ ybuf, const int* __restrict__ rowidx,
    const float* __restrict__ topk_s, float* __restrict__ out)
{
    const int t = blockIdx.x;
    const int d0 = threadIdx.x * 4;
    const int r0 = rowidx[t*2+0], r1 = rowidx[t*2+1];
    const float s0 = topk_s[t*2+0], s1 = topk_s[t*2+1];
    bf16x4 y0 = *(const bf16x4*)(ybuf + (size_t)r0 * D_DIM + d0);
    bf16x4 y1 = *(const bf16x4*)(ybuf + (size_t)r1 * D_DIM + d0);
    float4 o;
    o.x = s0 * (float)y0[0] + s1 * (float)y1[0];
    o.y = s0 * (float)y0[1] + s1 * (float)y1[1];
    o.z = s0 * (float)y0[2] + s1 * (float)y1[2];
    o.w = s0 * (float)y0[3] + s1 * (float)y1[3];
    *(float4*)(out + (size_t)t * D_DIM + d0) = o;
}

extern "C" void kernel_launch(void* const* d_in, const int* in_sizes, int n_in,
                              void* d_out, int out_size, void* d_ws, size_t ws_size,
                              hipStream_t stream) {
    const float* x  = (const float*)d_in[0];
    const float* Wg = (const float*)d_in[1];
    const float* W1 = (const float*)d_in[2];
    const float* b1 = (const float*)d_in[3];
    const float* W2 = (const float*)d_in[4];
    const float* b2 = (const float*)d_in[5];
    float* out = (float*)d_out;
    char* ws = (char*)d_ws;

    int*   mbTot  = (int*)  (ws + OFF_MBTOT);
    int*   mb2e   = (int*)  (ws + OFF_MB2E);
    int*   mbrow0 = (int*)  (ws + OFF_MBROW0);
    int*   topk_e = (int*)  (ws + OFF_TOPKE);
    float* topk_s = (float*)(ws + OFF_TOPKS);
    int*   tok    = (int*)  (ws + OFF_TOK);
    int*   rowidx = (int*)  (ws + OFF_ROWIDX);
    __bf16* xb   = (__bf16*)(ws + OFF_XB);
    __bf16* W1T  = (__bf16*)(ws + OFF_W1T);
    __bf16* W2T  = (__bf16*)(ws + OFF_W2T);
    __bf16* hbuf = (__bf16*)(ws + OFF_HBUF);
    __bf16* ybuf = (__bf16*)(ws + OFF_YBUF);

    // zero tok (pad rows -> tok=0). tables fully written by k_sort.
    hipMemsetAsync(ws + OFF_TOK, 0, MAX_ROWS * sizeof(int), stream);

    k_router_cvt<<<T_TOK/4, 256, 0, stream>>>(x, Wg, xb, topk_e, topk_s);
    k_sort      <<<1, 512, 0, stream>>>(topk_e, mbTot, mb2e, mbrow0, tok, rowidx);
    k_transpose <<<dim3(D_DIM/64, H_DIM/64, E_NUM), 256, 0, stream>>>(W1, W1T, D_DIM, H_DIM);
    k_transpose <<<dim3(H_DIM/64, D_DIM/64, E_NUM), 256, 0, stream>>>(W2, W2T, H_DIM, D_DIM);

    k_gemm<D_DIM, 8, true,  true ><<<MAX_MB * 8, 512, 0, stream>>>(
        xb, W1T, b1, tok, mb2e, mbrow0, mbTot, hbuf);
    k_gemm<H_DIM, 4, false, false><<<MAX_MB * 4, 512, 0, stream>>>(
        hbuf, W2T, b2, tok, mb2e, mbrow0, mbTot, ybuf);

    k_combine<<<T_TOK, 256, 0, stream>>>(ybuf, rowidx, topk_s, out);
}